// Round 4
// baseline (12872.786 us; speedup 1.0000x reference)
//
#include <hip/hip_runtime.h>
#include <cstdint>
#include <cstddef>

#define BATCH   65536
#define RANK_K  32769   // sorted_desc[32768] == 32769-th largest (1-indexed)
#define CAND_CAP 4096

#define GLOBAL_AS __attribute__((address_space(1)))
#define LDS_AS    __attribute__((address_space(3)))

__device__ __forceinline__ void dma16(const float* g, float* l) {
    // async global->LDS, 16B per lane, dest = wave-uniform base + lane*16 (sink-proof, no VGPR)
    __builtin_amdgcn_global_load_lds((const GLOBAL_AS void*)g, (LDS_AS void*)l, 16, 0, 0);
}

// ============ big GEMM (layers 1&2): C = relu((A*rowmask) @ B + bias) + per-row sumsq partials ============
// BM=256, BN=128, BK=16, 256 threads, 16x8/thread. Round-4: global_load_lds double-buffer
// (m97 pattern). LDS layouts: A row-major [256][16], B [16][128], both unpadded (DMA contiguity).
// Inner loop blocked 4-kk so A reads are b128. Per-element FMA order unchanged (k ascending)
// -> bit-identical h / norms / masks vs validated round-2 kernel.
template<bool MASKED>
__global__ __launch_bounds__(256, 3)
void gemm_relu_norm(const float* __restrict__ A, const float* __restrict__ B,
                    const float* __restrict__ bias,
                    const float* __restrict__ prevNorms, const unsigned* __restrict__ thrKey,
                    float* __restrict__ C, float* __restrict__ normPart,
                    const int N, const int K)
{
    __shared__ float smem[12288];        // 2 x (A 4096 + B 2048) floats = 48 KiB; red overlays after

    const int t    = threadIdx.x;
    const int w    = t >> 6;             // wave 0..3
    const int l    = t & 63;             // lane
    const int tr   = t >> 4;             // 0..15 row group (16 rows each)
    const int tc   = t & 15;             // 0..15 col group (8 cols each)
    const int row0 = blockIdx.x * 256;
    const int col0 = blockIdx.y * 128;

    float mrow[16];
    if (MASKED) {
        const unsigned tk = thrKey[0];
        #pragma unroll
        for (int i = 0; i < 16; ++i)
            mrow[i] = (__float_as_uint(prevNorms[row0 + tr*16 + i]) > tk) ? 1.0f : 0.0f;
    }

    float acc[16][8];
    #pragma unroll
    for (int i = 0; i < 16; ++i)
        #pragma unroll
        for (int j = 0; j < 8; ++j) acc[i][j] = 0.0f;

    const int NT = K >> 4;

    auto stage = [&](int tile, int bsel) {
        float* dstA = smem + bsel * 6144;
        float* dstB = dstA + 4096;
        const int k0 = tile << 4;
        #pragma unroll
        for (int c = 0; c < 4; ++c) {                 // A: 16 KiB, 4 wave-chunks of 1 KiB per wave
            const int m = w * 4 + c;
            const int r = m * 16 + (l >> 2);
            dma16(A + (size_t)(row0 + r) * K + k0 + (l & 3) * 4, dstA + m * 256);
        }
        #pragma unroll
        for (int c = 0; c < 2; ++c) {                 // B: 8 KiB, 2 wave-chunks per wave
            const int m = w * 2 + c;
            const int kr = 2 * m + (l >> 5);
            dma16(B + (size_t)(k0 + kr) * N + col0 + (l & 31) * 4, dstB + m * 256);
        }
    };

    stage(0, 0);
    for (int tile = 0; tile < NT; ++tile) {
        __syncthreads();                               // drains DMA(tile) (issued ~1 compute-phase ago)
        if (tile + 1 < NT) stage(tile + 1, (tile + 1) & 1);
        const float* Acur = smem + (tile & 1) * 6144;
        const float* Bcur = Acur + 4096;
        #pragma unroll
        for (int g4 = 0; g4 < 4; ++g4) {               // 4 kk per group, k ascending overall
            float b_[4][8];
            #pragma unroll
            for (int kk = 0; kk < 4; ++kk) {
                *(float4*)&b_[kk][0] = *(const float4*)&Bcur[(g4*4 + kk) * 128 + tc*8];
                *(float4*)&b_[kk][4] = *(const float4*)&Bcur[(g4*4 + kk) * 128 + tc*8 + 4];
            }
            #pragma unroll
            for (int i = 0; i < 16; ++i) {
                float4 a4 = *(const float4*)&Acur[(tr*16 + i) * 16 + g4*4];
                if (MASKED) { a4.x *= mrow[i]; a4.y *= mrow[i]; a4.z *= mrow[i]; a4.w *= mrow[i]; }
                float ar[4] = {a4.x, a4.y, a4.z, a4.w};
                #pragma unroll
                for (int kk = 0; kk < 4; ++kk)
                    #pragma unroll
                    for (int j = 0; j < 8; ++j)
                        acc[i][j] = fmaf(ar[kk], b_[kk][j], acc[i][j]);
            }
        }
    }
    __syncthreads();

    float bv[8];
    #pragma unroll
    for (int j = 0; j < 8; ++j) bv[j] = bias[col0 + tc*8 + j];

    float rowsum[16];
    #pragma unroll
    for (int i = 0; i < 16; ++i) {
        float s = 0.0f;
        #pragma unroll
        for (int j = 0; j < 8; ++j) {
            float v = fmaxf(acc[i][j] + bv[j], 0.0f);   // dot, +bias, relu (matches ref)
            acc[i][j] = v;
            s = fmaf(v, v, s);
        }
        rowsum[i] = s;
    }

    #pragma unroll
    for (int i = 0; i < 16; ++i) {
        const size_t row = (size_t)(row0 + tr*16 + i);
        *(float4*)&C[row * N + col0 + tc*8]     = *(float4*)&acc[i][0];
        *(float4*)&C[row * N + col0 + tc*8 + 4] = *(float4*)&acc[i][4];
    }

    float (*red)[17] = (float(*)[17])smem;             // 17408 B overlay, safe after barrier
    #pragma unroll
    for (int i = 0; i < 16; ++i) red[tr*16 + i][tc] = rowsum[i];
    __syncthreads();
    {
        float s = 0.0f;
        #pragma unroll
        for (int x = 0; x < 16; ++x) s += red[t][x];    // fixed order -> deterministic
        normPart[(size_t)blockIdx.y * BATCH + row0 + t] = s;
    }
}

// ============ deterministic partial-sum -> norm (sqrt in double = correctly-rounded fp32 sqrt) ============
__global__ __launch_bounds__(256)
void reduce_norms_kernel(const float* __restrict__ part, float* __restrict__ norms, const int nPart)
{
    const int i = blockIdx.x * 256 + threadIdx.x;
    float s = 0.0f;
    for (int p = 0; p < nPart; ++p) s += part[(size_t)p * BATCH + i];
    norms[i] = (float)sqrt((double)s);
}

// ============ exact 32769-th-largest: adaptive histogram + in-bin candidate rank (single WG) ============
__global__ __launch_bounds__(1024)
void select_kernel(const float* __restrict__ norms, unsigned* __restrict__ thrOut)
{
    __shared__ unsigned hist[4096];
    __shared__ unsigned ssum[1024];
    __shared__ unsigned cand[CAND_CAP];
    __shared__ unsigned wmin[16], wmax[16], gsum[16], wsum[16];
    __shared__ unsigned sMin, sBin, sRank, sCount, sThr, sApp;
    __shared__ int      sShift;

    const int t = threadIdx.x;
    unsigned key[64];
    const float4* n4p = (const float4*)norms;
    #pragma unroll
    for (int i = 0; i < 16; ++i) {
        float4 v = n4p[i * 1024 + t];
        key[i*4+0] = __float_as_uint(v.x);
        key[i*4+1] = __float_as_uint(v.y);
        key[i*4+2] = __float_as_uint(v.z);
        key[i*4+3] = __float_as_uint(v.w);          // nonneg -> monotone uint order
    }

    // min/max reduce
    unsigned mn = key[0], mx = key[0];
    #pragma unroll
    for (int i = 1; i < 64; ++i) { mn = min(mn, key[i]); mx = max(mx, key[i]); }
    #pragma unroll
    for (int off = 32; off > 0; off >>= 1) {
        mn = min(mn, (unsigned)__shfl_down((int)mn, off, 64));
        mx = max(mx, (unsigned)__shfl_down((int)mx, off, 64));
    }
    if ((t & 63) == 0) { wmin[t >> 6] = mn; wmax[t >> 6] = mx; }
    hist[t] = 0; hist[t+1024] = 0; hist[t+2048] = 0; hist[t+3072] = 0;
    __syncthreads();
    if (t == 0) {
        unsigned m0 = wmin[0], m1 = wmax[0];
        for (int q = 1; q < 16; ++q) { m0 = min(m0, wmin[q]); m1 = max(m1, wmax[q]); }
        const unsigned span = m1 - m0;
        sMin = m0;
        sShift = (span > 4095u) ? (20 - __clz(span)) : 0;   // bins = span>>shift <= 4095
        sApp = 0;
    }
    __syncthreads();
    const unsigned mn_u = sMin;
    const int sh = sShift;
    #pragma unroll
    for (int i = 0; i < 64; ++i) atomicAdd(&hist[(key[i] - mn_u) >> sh], 1u);
    __syncthreads();
    ssum[t] = hist[4*t] + hist[4*t+1] + hist[4*t+2] + hist[4*t+3];
    __syncthreads();
    if (t < 16) {
        unsigned g = 0;
        for (int q = 0; q < 64; ++q) g += ssum[t*64 + q];
        gsum[t] = g;
    }
    __syncthreads();
    if (t == 0) {
        unsigned cum = 0; int g, q, b;
        for (g = 15; g >= 0; --g) { if (cum + gsum[g] >= RANK_K) break; cum += gsum[g]; }
        for (q = g*64 + 63; q >= g*64; --q) { if (cum + ssum[q] >= RANK_K) break; cum += ssum[q]; }
        for (b = q*4 + 3; b >= q*4; --b) { if (cum + hist[b] >= RANK_K) break; cum += hist[b]; }
        sBin = (unsigned)b; sRank = RANK_K - cum; sCount = hist[b];
    }
    __syncthreads();
    const unsigned b = sBin, cnt = sCount;
    const int r = (int)sRank;

    if (cnt <= CAND_CAP) {
        #pragma unroll
        for (int i = 0; i < 64; ++i)
            if (((key[i] - mn_u) >> sh) == b) { unsigned p = atomicAdd(&sApp, 1u); cand[p] = key[i]; }
        __syncthreads();
        for (int j = t; j < (int)cnt; j += 1024) {
            const unsigned kj = cand[j];
            int gq = 0, eq = 0;
            for (int i = 0; i < (int)cnt; ++i) { const unsigned ki = cand[i]; gq += ki > kj; eq += ki == kj; }
            if (gq < r && r <= gq + eq) sThr = kj;     // all writers (ties) write same value
        }
        __syncthreads();
    } else {
        // fallback (pathological clustering): binary search within bin's subrange
        unsigned lo = mn_u + (b << sh);
        unsigned hi = lo + ((sh > 0) ? ((1u << sh) - 1u) : 0u);
        while (lo < hi) {
            const unsigned mid = lo + ((hi - lo) >> 1);
            int c = 0;
            #pragma unroll
            for (int i = 0; i < 64; ++i) c += (key[i] > mid) ? 1 : 0;
            #pragma unroll
            for (int off = 32; off > 0; off >>= 1) c += __shfl_down(c, off, 64);
            if ((t & 63) == 0) wsum[t >> 6] = (unsigned)c;
            __syncthreads();
            int total = 0;
            #pragma unroll
            for (int q = 0; q < 16; ++q) total += (int)wsum[q];
            if (total < RANK_K) hi = mid; else lo = mid + 1;
            __syncthreads();
        }
        if (t == 0) sThr = lo;
        __syncthreads();
    }
    if (t == 0) thrOut[0] = sThr;
}

// ============ layer 3: h3 = relu((h2*m2) @ W3[256x10] + b3), full row norms ============
__global__ __launch_bounds__(256)
void layer3_kernel(const float* __restrict__ h2, const float* __restrict__ W3,
                   const float* __restrict__ b3,
                   const float* __restrict__ n2, const unsigned* __restrict__ thr2,
                   float* __restrict__ h3, float* __restrict__ norms3)
{
    __shared__ float wT[10][260];
    __shared__ float red[64][5];

    const int t    = threadIdx.x;
    const int r    = t & 63;
    const int g    = t >> 6;
    const int j0   = g * 3;
    const int nj   = (g == 3) ? 1 : 3;
    const int row0 = blockIdx.x * 64;
    const int row  = row0 + r;

    for (int e = t; e < 2560; e += 256) wT[e % 10][e / 10] = W3[e];
    __syncthreads();

    const float m = (__float_as_uint(n2[row]) > thr2[0]) ? 1.0f : 0.0f;
    const float* hrow = h2 + (size_t)row * 256;

    float acc[3] = {0.0f, 0.0f, 0.0f};
    for (int k = 0; k < 256; k += 4) {
        float4 v = *(const float4*)(hrow + k);
        v.x *= m; v.y *= m; v.z *= m; v.w *= m;
        float4 w0 = *(const float4*)&wT[j0][k];
        acc[0] += v.x*w0.x + v.y*w0.y + v.z*w0.z + v.w*w0.w;
        if (nj > 1) {
            float4 w1 = *(const float4*)&wT[j0+1][k];
            acc[1] += v.x*w1.x + v.y*w1.y + v.z*w1.z + v.w*w1.w;
            float4 w2 = *(const float4*)&wT[j0+2][k];
            acc[2] += v.x*w2.x + v.y*w2.y + v.z*w2.z + v.w*w2.w;
        }
    }

    float ss = 0.0f;
    for (int jj = 0; jj < nj; ++jj) {
        float v = fmaxf(acc[jj] + b3[j0 + jj], 0.0f);
        h3[(size_t)row * 10 + j0 + jj] = v;
        ss += v * v;
    }
    red[r][g] = ss;
    __syncthreads();
    if (t < 64) {
        float s = red[t][0] + red[t][1] + red[t][2] + red[t][3];
        norms3[row0 + t] = (float)sqrt((double)s);
    }
}

// ============ layer 4: h4 = (h3*m3) @ W4[10x10] + b4 (no relu), norms ============
__global__ __launch_bounds__(256)
void layer4_kernel(const float* __restrict__ h3, const float* __restrict__ W4,
                   const float* __restrict__ b4,
                   const float* __restrict__ n3, const unsigned* __restrict__ thr3,
                   float* __restrict__ h4, float* __restrict__ norms4)
{
    __shared__ float w[100];
    __shared__ float bb[10];
    const int t = threadIdx.x;
    if (t < 100) w[t] = W4[t];
    if (t < 10)  bb[t] = b4[t];
    __syncthreads();

    const int row = blockIdx.x * 256 + t;
    const float m = (__float_as_uint(n3[row]) > thr3[0]) ? 1.0f : 0.0f;
    const float* hr = h3 + (size_t)row * 10;
    float v[10];
    #pragma unroll
    for (int k = 0; k < 10; ++k) v[k] = hr[k] * m;

    float s = 0.0f;
    #pragma unroll
    for (int j = 0; j < 10; ++j) {
        float a = 0.0f;
        #pragma unroll
        for (int k = 0; k < 10; ++k) a = fmaf(v[k], w[k*10 + j], a);
        a += bb[j];
        h4[(size_t)row * 10 + j] = a;
        s = fmaf(a, a, s);
    }
    norms4[row] = (float)sqrt((double)s);
}

// ============ final: out = softmax(h4 * m4) ============
__global__ __launch_bounds__(256)
void softmax_kernel(const float* __restrict__ h4,
                    const float* __restrict__ n4, const unsigned* __restrict__ thr4,
                    float* __restrict__ out)
{
    const int t   = threadIdx.x;
    const int row = blockIdx.x * 256 + t;
    const float m = (__float_as_uint(n4[row]) > thr4[0]) ? 1.0f : 0.0f;
    const float* hr = h4 + (size_t)row * 10;
    float v[10];
    #pragma unroll
    for (int k = 0; k < 10; ++k) v[k] = hr[k] * m;
    float mx = v[0];
    #pragma unroll
    for (int k = 1; k < 10; ++k) mx = fmaxf(mx, v[k]);
    float e[10];
    float s = 0.0f;
    #pragma unroll
    for (int k = 0; k < 10; ++k) { e[k] = expf(v[k] - mx); s += e[k]; }
    const float inv = 1.0f / s;
    #pragma unroll
    for (int k = 0; k < 10; ++k) out[(size_t)row * 10 + k] = e[k] * inv;
}

// ============ materialize all four masks into d_out ============
__global__ __launch_bounds__(256)
void masks_kernel(const float* __restrict__ n1, const float* __restrict__ n2,
                  const float* __restrict__ n3, const float* __restrict__ n4,
                  const unsigned* __restrict__ thr,
                  float* __restrict__ m1, float* __restrict__ m2,
                  float* __restrict__ m3, float* __restrict__ m4)
{
    const int i = blockIdx.x * 256 + threadIdx.x;
    m1[i] = (__float_as_uint(n1[i]) > thr[0]) ? 1.0f : 0.0f;
    m2[i] = (__float_as_uint(n2[i]) > thr[1]) ? 1.0f : 0.0f;
    m3[i] = (__float_as_uint(n3[i]) > thr[2]) ? 1.0f : 0.0f;
    m4[i] = (__float_as_uint(n4[i]) > thr[3]) ? 1.0f : 0.0f;
}

extern "C" void kernel_launch(void* const* d_in, const int* in_sizes, int n_in,
                              void* d_out, int out_size, void* d_ws, size_t ws_size,
                              hipStream_t stream)
{
    const float* x  = (const float*)d_in[0];
    const float* W1 = (const float*)d_in[1];
    const float* b1 = (const float*)d_in[2];
    const float* W2 = (const float*)d_in[3];
    const float* b2 = (const float*)d_in[4];
    const float* W3 = (const float*)d_in[5];
    const float* b3 = (const float*)d_in[6];
    const float* W4 = (const float*)d_in[7];
    const float* b4 = (const float*)d_in[8];

    float* out = (float*)d_out;                 // [65536,10]
    float* m1  = out + (size_t)BATCH * 10;      // [65536] each
    float* m2  = m1 + BATCH;
    float* m3  = m2 + BATCH;
    float* m4  = m3 + BATCH;

    float* ws    = (float*)d_ws;
    float* h1    = ws;                                  // 65536*512
    float* h2    = h1 + (size_t)BATCH * 512;            // 65536*256
    float* h3    = h2 + (size_t)BATCH * 256;            // 65536*10
    float* h4    = h3 + (size_t)BATCH * 10;             // 65536*10
    float* n1    = h4 + (size_t)BATCH * 10;             // 65536 x4
    float* n2    = n1 + BATCH;
    float* n3    = n2 + BATCH;
    float* n4    = n3 + BATCH;
    float* part  = n4 + BATCH;                          // 4*65536
    unsigned* thr = (unsigned*)(part + (size_t)4 * BATCH);  // 4 threshold keys

    // layer 1: x[65536,784] @ W1[784,512]
    gemm_relu_norm<false><<<dim3(256, 4), 256, 0, stream>>>(x, W1, b1, nullptr, nullptr, h1, part, 512, 784);
    reduce_norms_kernel<<<256, 256, 0, stream>>>(part, n1, 4);
    select_kernel<<<1, 1024, 0, stream>>>(n1, thr + 0);

    // layer 2: (h1*m1)[65536,512] @ W2[512,256]  (mask inline from n1/thr1)
    gemm_relu_norm<true><<<dim3(256, 2), 256, 0, stream>>>(h1, W2, b2, n1, thr + 0, h2, part, 256, 512);
    reduce_norms_kernel<<<256, 256, 0, stream>>>(part, n2, 2);
    select_kernel<<<1, 1024, 0, stream>>>(n2, thr + 1);

    // layer 3: (h2*m2)[65536,256] @ W3[256,10]
    layer3_kernel<<<1024, 256, 0, stream>>>(h2, W3, b3, n2, thr + 1, h3, n3);
    select_kernel<<<1, 1024, 0, stream>>>(n3, thr + 2);

    // layer 4: (h3*m3)[65536,10] @ W4[10,10] (no relu)
    layer4_kernel<<<256, 256, 0, stream>>>(h3, W4, b4, n3, thr + 2, h4, n4);
    select_kernel<<<1, 1024, 0, stream>>>(n4, thr + 3);

    // softmax(h4*m4)
    softmax_kernel<<<256, 256, 0, stream>>>(h4, n4, thr + 3, out);

    // masks m1..m4 -> d_out
    masks_kernel<<<256, 256, 0, stream>>>(n1, n2, n3, n4, thr, m1, m2, m3, m4);
}

// Round 5
// 3546.576 us; speedup vs baseline: 3.6296x; 3.6296x over previous
//
#include <hip/hip_runtime.h>
#include <cstdint>
#include <cstddef>

#define BATCH   65536
#define RANK_K  32769   // sorted_desc[32768] == 32769-th largest (1-indexed)
#define CAND_CAP 4096

// ============ big GEMM (layers 1&2): C = relu((A*rowmask) @ B + bias) + per-row sumsq partials ============
// BM=256, BN=128, BK=16, 256 threads, 16x8/thread. Round-5: LDS DOUBLE BUFFER, one barrier per
// tile; next-tile global loads issue after the barrier, ds_writes to the idle buffer sit between
// the two compute halves (covers HBM latency even if the scheduler sinks the loads).
// Per-element FMA chain (k ascending), bias->relu->square epilogue and 16-group row reduction are
// IDENTICAL to the validated round-2 kernel -> bit-identical h / norms / masks.
template<bool MASKED>
__global__ __launch_bounds__(256, 2)
void gemm_relu_norm(const float* __restrict__ A, const float* __restrict__ B,
                    const float* __restrict__ bias,
                    const float* __restrict__ prevNorms, const unsigned* __restrict__ thrKey,
                    float* __restrict__ C, float* __restrict__ normPart,
                    const int N, const int K)
{
    // 2 x (As[16][260] + Bs[16][136]) = 12672 floats = 50688 B; red[256][17] overlays afterward
    __shared__ float smem[12672];

    const int t    = threadIdx.x;
    const int tr   = t >> 4;          // 0..15 row group (16 rows each)
    const int tc   = t & 15;          // 0..15 col group (8 cols each)
    const int row0 = blockIdx.x * 256;
    const int col0 = blockIdx.y * 128;

    // A-load: thread t stages row (row0+t), 16 consecutive k per tile
    const float* Aptr = A + (size_t)(row0 + t) * K;
    // B-load: 16 k-rows x 128 cols; thread: k=t>>4, cols (t&15)*8..+7
    const int bk = t >> 4;
    const int bc = (t & 15) * 8;
    const float* Bptr = B + (size_t)bk * N + col0 + bc;

    float scale = 1.0f;
    if (MASKED) scale = (__float_as_uint(prevNorms[row0 + t]) > thrKey[0]) ? 1.0f : 0.0f;

    float acc[16][8];
    #pragma unroll
    for (int i = 0; i < 16; ++i)
        #pragma unroll
        for (int j = 0; j < 8; ++j) acc[i][j] = 0.0f;

    const int NT = K >> 4;

    auto writeLDS = [&](int bsel, float4 a0, float4 a1, float4 a2, float4 a3,
                        float4 b0, float4 b1) {
        float (*As)[260] = (float(*)[260])(smem + bsel * 6336);
        float (*Bs)[136] = (float(*)[136])(smem + bsel * 6336 + 16*260);
        As[ 0][t] = a0.x*scale; As[ 1][t] = a0.y*scale; As[ 2][t] = a0.z*scale; As[ 3][t] = a0.w*scale;
        As[ 4][t] = a1.x*scale; As[ 5][t] = a1.y*scale; As[ 6][t] = a1.z*scale; As[ 7][t] = a1.w*scale;
        As[ 8][t] = a2.x*scale; As[ 9][t] = a2.y*scale; As[10][t] = a2.z*scale; As[11][t] = a2.w*scale;
        As[12][t] = a3.x*scale; As[13][t] = a3.y*scale; As[14][t] = a3.z*scale; As[15][t] = a3.w*scale;
        *(float4*)&Bs[bk][bc]     = b0;
        *(float4*)&Bs[bk][bc + 4] = b1;
    };

    // compute half: g4 groups [g4lo, g4hi)
    auto computeHalf = [&](int bsel, int g4lo, int g4hi) {
        const float (*As)[260] = (const float(*)[260])(smem + bsel * 6336);
        const float (*Bs)[136] = (const float(*)[136])(smem + bsel * 6336 + 16*260);
        #pragma unroll
        for (int g4 = 0; g4 < 2; ++g4) {
            const int kkBase = (g4lo + g4) * 4;
            #pragma unroll
            for (int kq = 0; kq < 4; ++kq) {
                const int kk = kkBase + kq;
                float a_[16], b_[8];
                *(float4*)&a_[0]  = *(const float4*)&As[kk][tr*16];
                *(float4*)&a_[4]  = *(const float4*)&As[kk][tr*16 + 4];
                *(float4*)&a_[8]  = *(const float4*)&As[kk][tr*16 + 8];
                *(float4*)&a_[12] = *(const float4*)&As[kk][tr*16 + 12];
                *(float4*)&b_[0]  = *(const float4*)&Bs[kk][tc*8];
                *(float4*)&b_[4]  = *(const float4*)&Bs[kk][tc*8 + 4];
                #pragma unroll
                for (int i = 0; i < 16; ++i)
                    #pragma unroll
                    for (int j = 0; j < 8; ++j)
                        acc[i][j] = fmaf(a_[i], b_[j], acc[i][j]);
            }
        }
    };

    // stage tile 0 into buffer 0
    {
        float4 a0 = *(const float4*)(Aptr + 0);
        float4 a1 = *(const float4*)(Aptr + 4);
        float4 a2 = *(const float4*)(Aptr + 8);
        float4 a3 = *(const float4*)(Aptr + 12);
        float4 b0 = *(const float4*)(Bptr + 0);
        float4 b1 = *(const float4*)(Bptr + 4);
        writeLDS(0, a0, a1, a2, a3, b0, b1);
    }

    for (int tile = 0; tile < NT; ++tile) {
        __syncthreads();                    // buf[tile&1] fully written; prev compute fully done
        const int cur = tile & 1;
        if (tile + 1 < NT) {
            const int kn = (tile + 1) << 4;
            float4 a0 = *(const float4*)(Aptr + kn);
            float4 a1 = *(const float4*)(Aptr + kn + 4);
            float4 a2 = *(const float4*)(Aptr + kn + 8);
            float4 a3 = *(const float4*)(Aptr + kn + 12);
            float4 b0 = *(const float4*)(Bptr + (size_t)kn * N);
            float4 b1 = *(const float4*)(Bptr + (size_t)kn * N + 4);
            computeHalf(cur, 0, 2);         // first half of tile while loads are in flight
            writeLDS(1 - cur, a0, a1, a2, a3, b0, b1);   // into idle buffer (no barrier needed)
            computeHalf(cur, 2, 4);         // second half
        } else {
            computeHalf(cur, 0, 2);
            computeHalf(cur, 2, 4);
        }
    }
    __syncthreads();

    float bv[8];
    #pragma unroll
    for (int j = 0; j < 8; ++j) bv[j] = bias[col0 + tc*8 + j];

    float rowsum[16];
    #pragma unroll
    for (int i = 0; i < 16; ++i) {
        float s = 0.0f;
        #pragma unroll
        for (int j = 0; j < 8; ++j) {
            float v = fmaxf(acc[i][j] + bv[j], 0.0f);   // dot, +bias, relu (matches ref)
            acc[i][j] = v;
            s = fmaf(v, v, s);
        }
        rowsum[i] = s;
    }

    #pragma unroll
    for (int i = 0; i < 16; ++i) {
        const size_t row = (size_t)(row0 + tr*16 + i);
        *(float4*)&C[row * N + col0 + tc*8]     = *(float4*)&acc[i][0];
        *(float4*)&C[row * N + col0 + tc*8 + 4] = *(float4*)&acc[i][4];
    }

    float (*red)[17] = (float(*)[17])smem;             // 17408 B overlay, safe after barrier
    #pragma unroll
    for (int i = 0; i < 16; ++i) red[tr*16 + i][tc] = rowsum[i];
    __syncthreads();
    {
        float s = 0.0f;
        #pragma unroll
        for (int x = 0; x < 16; ++x) s += red[t][x];    // fixed order -> deterministic
        normPart[(size_t)blockIdx.y * BATCH + row0 + t] = s;
    }
}

// ============ deterministic partial-sum -> norm (sqrt in double = correctly-rounded fp32 sqrt) ============
__global__ __launch_bounds__(256)
void reduce_norms_kernel(const float* __restrict__ part, float* __restrict__ norms, const int nPart)
{
    const int i = blockIdx.x * 256 + threadIdx.x;
    float s = 0.0f;
    for (int p = 0; p < nPart; ++p) s += part[(size_t)p * BATCH + i];
    norms[i] = (float)sqrt((double)s);
}

// ============ exact 32769-th-largest: adaptive histogram + in-bin candidate rank (single WG) ============
__global__ __launch_bounds__(1024)
void select_kernel(const float* __restrict__ norms, unsigned* __restrict__ thrOut)
{
    __shared__ unsigned hist[4096];
    __shared__ unsigned ssum[1024];
    __shared__ unsigned cand[CAND_CAP];
    __shared__ unsigned wmin[16], wmax[16], gsum[16], wsum[16];
    __shared__ unsigned sMin, sBin, sRank, sCount, sThr, sApp;
    __shared__ int      sShift;

    const int t = threadIdx.x;
    unsigned key[64];
    const float4* n4p = (const float4*)norms;
    #pragma unroll
    for (int i = 0; i < 16; ++i) {
        float4 v = n4p[i * 1024 + t];
        key[i*4+0] = __float_as_uint(v.x);
        key[i*4+1] = __float_as_uint(v.y);
        key[i*4+2] = __float_as_uint(v.z);
        key[i*4+3] = __float_as_uint(v.w);          // nonneg -> monotone uint order
    }

    unsigned mn = key[0], mx = key[0];
    #pragma unroll
    for (int i = 1; i < 64; ++i) { mn = min(mn, key[i]); mx = max(mx, key[i]); }
    #pragma unroll
    for (int off = 32; off > 0; off >>= 1) {
        mn = min(mn, (unsigned)__shfl_down((int)mn, off, 64));
        mx = max(mx, (unsigned)__shfl_down((int)mx, off, 64));
    }
    if ((t & 63) == 0) { wmin[t >> 6] = mn; wmax[t >> 6] = mx; }
    hist[t] = 0; hist[t+1024] = 0; hist[t+2048] = 0; hist[t+3072] = 0;
    __syncthreads();
    if (t == 0) {
        unsigned m0 = wmin[0], m1 = wmax[0];
        for (int q = 1; q < 16; ++q) { m0 = min(m0, wmin[q]); m1 = max(m1, wmax[q]); }
        const unsigned span = m1 - m0;
        sMin = m0;
        sShift = (span > 4095u) ? (20 - __clz(span)) : 0;   // bins = span>>shift <= 4095
        sApp = 0;
    }
    __syncthreads();
    const unsigned mn_u = sMin;
    const int sh = sShift;
    #pragma unroll
    for (int i = 0; i < 64; ++i) atomicAdd(&hist[(key[i] - mn_u) >> sh], 1u);
    __syncthreads();
    ssum[t] = hist[4*t] + hist[4*t+1] + hist[4*t+2] + hist[4*t+3];
    __syncthreads();
    if (t < 16) {
        unsigned g = 0;
        for (int q = 0; q < 64; ++q) g += ssum[t*64 + q];
        gsum[t] = g;
    }
    __syncthreads();
    if (t == 0) {
        unsigned cum = 0; int g, q, b;
        for (g = 15; g >= 0; --g) { if (cum + gsum[g] >= RANK_K) break; cum += gsum[g]; }
        for (q = g*64 + 63; q >= g*64; --q) { if (cum + ssum[q] >= RANK_K) break; cum += ssum[q]; }
        for (b = q*4 + 3; b >= q*4; --b) { if (cum + hist[b] >= RANK_K) break; cum += hist[b]; }
        sBin = (unsigned)b; sRank = RANK_K - cum; sCount = hist[b];
    }
    __syncthreads();
    const unsigned b = sBin, cnt = sCount;
    const int r = (int)sRank;

    if (cnt <= CAND_CAP) {
        #pragma unroll
        for (int i = 0; i < 64; ++i)
            if (((key[i] - mn_u) >> sh) == b) { unsigned p = atomicAdd(&sApp, 1u); cand[p] = key[i]; }
        __syncthreads();
        for (int j = t; j < (int)cnt; j += 1024) {
            const unsigned kj = cand[j];
            int gq = 0, eq = 0;
            for (int i = 0; i < (int)cnt; ++i) { const unsigned ki = cand[i]; gq += ki > kj; eq += ki == kj; }
            if (gq < r && r <= gq + eq) sThr = kj;     // all writers (ties) write same value
        }
        __syncthreads();
    } else {
        // fallback (pathological clustering): binary search within bin's subrange
        unsigned lo = mn_u + (b << sh);
        unsigned hi = lo + ((sh > 0) ? ((1u << sh) - 1u) : 0u);
        while (lo < hi) {
            const unsigned mid = lo + ((hi - lo) >> 1);
            int c = 0;
            #pragma unroll
            for (int i = 0; i < 64; ++i) c += (key[i] > mid) ? 1 : 0;
            #pragma unroll
            for (int off = 32; off > 0; off >>= 1) c += __shfl_down(c, off, 64);
            if ((t & 63) == 0) wsum[t >> 6] = (unsigned)c;
            __syncthreads();
            int total = 0;
            #pragma unroll
            for (int q = 0; q < 16; ++q) total += (int)wsum[q];
            if (total < RANK_K) hi = mid; else lo = mid + 1;
            __syncthreads();
        }
        if (t == 0) sThr = lo;
        __syncthreads();
    }
    if (t == 0) thrOut[0] = sThr;
}

// ============ layer 3: h3 = relu((h2*m2) @ W3[256x10] + b3), full row norms ============
__global__ __launch_bounds__(256)
void layer3_kernel(const float* __restrict__ h2, const float* __restrict__ W3,
                   const float* __restrict__ b3,
                   const float* __restrict__ n2, const unsigned* __restrict__ thr2,
                   float* __restrict__ h3, float* __restrict__ norms3)
{
    __shared__ float wT[10][260];
    __shared__ float red[64][5];

    const int t    = threadIdx.x;
    const int r    = t & 63;
    const int g    = t >> 6;
    const int j0   = g * 3;
    const int nj   = (g == 3) ? 1 : 3;
    const int row0 = blockIdx.x * 64;
    const int row  = row0 + r;

    for (int e = t; e < 2560; e += 256) wT[e % 10][e / 10] = W3[e];
    __syncthreads();

    const float m = (__float_as_uint(n2[row]) > thr2[0]) ? 1.0f : 0.0f;
    const float* hrow = h2 + (size_t)row * 256;

    float acc[3] = {0.0f, 0.0f, 0.0f};
    for (int k = 0; k < 256; k += 4) {
        float4 v = *(const float4*)(hrow + k);
        v.x *= m; v.y *= m; v.z *= m; v.w *= m;
        float4 w0 = *(const float4*)&wT[j0][k];
        acc[0] += v.x*w0.x + v.y*w0.y + v.z*w0.z + v.w*w0.w;
        if (nj > 1) {
            float4 w1 = *(const float4*)&wT[j0+1][k];
            acc[1] += v.x*w1.x + v.y*w1.y + v.z*w1.z + v.w*w1.w;
            float4 w2 = *(const float4*)&wT[j0+2][k];
            acc[2] += v.x*w2.x + v.y*w2.y + v.z*w2.z + v.w*w2.w;
        }
    }

    float ss = 0.0f;
    for (int jj = 0; jj < nj; ++jj) {
        float v = fmaxf(acc[jj] + b3[j0 + jj], 0.0f);
        h3[(size_t)row * 10 + j0 + jj] = v;
        ss += v * v;
    }
    red[r][g] = ss;
    __syncthreads();
    if (t < 64) {
        float s = red[t][0] + red[t][1] + red[t][2] + red[t][3];
        norms3[row0 + t] = (float)sqrt((double)s);
    }
}

// ============ layer 4: h4 = (h3*m3) @ W4[10x10] + b4 (no relu), norms ============
__global__ __launch_bounds__(256)
void layer4_kernel(const float* __restrict__ h3, const float* __restrict__ W4,
                   const float* __restrict__ b4,
                   const float* __restrict__ n3, const unsigned* __restrict__ thr3,
                   float* __restrict__ h4, float* __restrict__ norms4)
{
    __shared__ float w[100];
    __shared__ float bb[10];
    const int t = threadIdx.x;
    if (t < 100) w[t] = W4[t];
    if (t < 10)  bb[t] = b4[t];
    __syncthreads();

    const int row = blockIdx.x * 256 + t;
    const float m = (__float_as_uint(n3[row]) > thr3[0]) ? 1.0f : 0.0f;
    const float* hr = h3 + (size_t)row * 10;
    float v[10];
    #pragma unroll
    for (int k = 0; k < 10; ++k) v[k] = hr[k] * m;

    float s = 0.0f;
    #pragma unroll
    for (int j = 0; j < 10; ++j) {
        float a = 0.0f;
        #pragma unroll
        for (int k = 0; k < 10; ++k) a = fmaf(v[k], w[k*10 + j], a);
        a += bb[j];
        h4[(size_t)row * 10 + j] = a;
        s = fmaf(a, a, s);
    }
    norms4[row] = (float)sqrt((double)s);
}

// ============ final: out = softmax(h4 * m4) ============
__global__ __launch_bounds__(256)
void softmax_kernel(const float* __restrict__ h4,
                    const float* __restrict__ n4, const unsigned* __restrict__ thr4,
                    float* __restrict__ out)
{
    const int t   = threadIdx.x;
    const int row = blockIdx.x * 256 + t;
    const float m = (__float_as_uint(n4[row]) > thr4[0]) ? 1.0f : 0.0f;
    const float* hr = h4 + (size_t)row * 10;
    float v[10];
    #pragma unroll
    for (int k = 0; k < 10; ++k) v[k] = hr[k] * m;
    float mx = v[0];
    #pragma unroll
    for (int k = 1; k < 10; ++k) mx = fmaxf(mx, v[k]);
    float e[10];
    float s = 0.0f;
    #pragma unroll
    for (int k = 0; k < 10; ++k) { e[k] = expf(v[k] - mx); s += e[k]; }
    const float inv = 1.0f / s;
    #pragma unroll
    for (int k = 0; k < 10; ++k) out[(size_t)row * 10 + k] = e[k] * inv;
}

// ============ materialize all four masks into d_out ============
__global__ __launch_bounds__(256)
void masks_kernel(const float* __restrict__ n1, const float* __restrict__ n2,
                  const float* __restrict__ n3, const float* __restrict__ n4,
                  const unsigned* __restrict__ thr,
                  float* __restrict__ m1, float* __restrict__ m2,
                  float* __restrict__ m3, float* __restrict__ m4)
{
    const int i = blockIdx.x * 256 + threadIdx.x;
    m1[i] = (__float_as_uint(n1[i]) > thr[0]) ? 1.0f : 0.0f;
    m2[i] = (__float_as_uint(n2[i]) > thr[1]) ? 1.0f : 0.0f;
    m3[i] = (__float_as_uint(n3[i]) > thr[2]) ? 1.0f : 0.0f;
    m4[i] = (__float_as_uint(n4[i]) > thr[3]) ? 1.0f : 0.0f;
}

extern "C" void kernel_launch(void* const* d_in, const int* in_sizes, int n_in,
                              void* d_out, int out_size, void* d_ws, size_t ws_size,
                              hipStream_t stream)
{
    const float* x  = (const float*)d_in[0];
    const float* W1 = (const float*)d_in[1];
    const float* b1 = (const float*)d_in[2];
    const float* W2 = (const float*)d_in[3];
    const float* b2 = (const float*)d_in[4];
    const float* W3 = (const float*)d_in[5];
    const float* b3 = (const float*)d_in[6];
    const float* W4 = (const float*)d_in[7];
    const float* b4 = (const float*)d_in[8];

    float* out = (float*)d_out;                 // [65536,10]
    float* m1  = out + (size_t)BATCH * 10;      // [65536] each
    float* m2  = m1 + BATCH;
    float* m3  = m2 + BATCH;
    float* m4  = m3 + BATCH;

    float* ws    = (float*)d_ws;
    float* h1    = ws;                                  // 65536*512
    float* h2    = h1 + (size_t)BATCH * 512;            // 65536*256
    float* h3    = h2 + (size_t)BATCH * 256;            // 65536*10
    float* h4    = h3 + (size_t)BATCH * 10;             // 65536*10
    float* n1    = h4 + (size_t)BATCH * 10;             // 65536 x4
    float* n2    = n1 + BATCH;
    float* n3    = n2 + BATCH;
    float* n4    = n3 + BATCH;
    float* part  = n4 + BATCH;                          // 4*65536
    unsigned* thr = (unsigned*)(part + (size_t)4 * BATCH);  // 4 threshold keys

    // layer 1: x[65536,784] @ W1[784,512]
    gemm_relu_norm<false><<<dim3(256, 4), 256, 0, stream>>>(x, W1, b1, nullptr, nullptr, h1, part, 512, 784);
    reduce_norms_kernel<<<256, 256, 0, stream>>>(part, n1, 4);
    select_kernel<<<1, 1024, 0, stream>>>(n1, thr + 0);

    // layer 2: (h1*m1)[65536,512] @ W2[512,256]  (mask inline from n1/thr1)
    gemm_relu_norm<true><<<dim3(256, 2), 256, 0, stream>>>(h1, W2, b2, n1, thr + 0, h2, part, 256, 512);
    reduce_norms_kernel<<<256, 256, 0, stream>>>(part, n2, 2);
    select_kernel<<<1, 1024, 0, stream>>>(n2, thr + 1);

    // layer 3: (h2*m2)[65536,256] @ W3[256,10]
    layer3_kernel<<<1024, 256, 0, stream>>>(h2, W3, b3, n2, thr + 1, h3, n3);
    select_kernel<<<1, 1024, 0, stream>>>(n3, thr + 2);

    // layer 4: (h3*m3)[65536,10] @ W4[10,10] (no relu)
    layer4_kernel<<<256, 256, 0, stream>>>(h3, W4, b4, n3, thr + 2, h4, n4);
    select_kernel<<<1, 1024, 0, stream>>>(n4, thr + 3);

    // softmax(h4*m4)
    softmax_kernel<<<256, 256, 0, stream>>>(h4, n4, thr + 3, out);

    // masks m1..m4 -> d_out
    masks_kernel<<<256, 256, 0, stream>>>(n1, n2, n3, n4, thr, m1, m2, m3, m4);
}

// Round 6
// 1258.842 us; speedup vs baseline: 10.2259x; 2.8173x over previous
//
#include <hip/hip_runtime.h>
#include <cstdint>
#include <cstddef>

#define BATCH   65536
#define RANK_K  32769   // sorted_desc[32768] == 32769-th largest (1-indexed)
#define CAND_CAP 4096

// ============ big GEMM (layers 1&2): C = relu((A*rowmask) @ B + bias) + per-row sumsq partials ============
// Round-6: EXACT round-2 structure (validated 623 us GEMM1, bit-identical outputs):
// BM=256, BN=128, BK=16, 256 threads, 16x8/thread, single LDS buffer,
// load -> ds_write -> barrier -> 16-kk compute -> barrier. No prefetch (r3/r4/r5 all showed
// any prefetch variant regresses: sink / DMA-scatter / spill). Mask applied inline from
// (prevNorms, thrKey) — validated in r4/r5. red[] overlays As/Bs after the final barrier.
template<bool MASKED>
__global__ __launch_bounds__(256, 2)
void gemm_relu_norm(const float* __restrict__ A, const float* __restrict__ B,
                    const float* __restrict__ bias,
                    const float* __restrict__ prevNorms, const unsigned* __restrict__ thrKey,
                    float* __restrict__ C, float* __restrict__ normPart,
                    const int N, const int K)
{
    __shared__ float smem[16*260 + 16*136];            // As | Bs ; red overlays after final barrier
    float (*As)[260] = (float(*)[260])smem;            // [k][row], padded
    float (*Bs)[136] = (float(*)[136])(smem + 16*260); // [k][col], padded

    const int t    = threadIdx.x;
    const int tr   = t >> 4;          // 0..15 row group (16 rows each)
    const int tc   = t & 15;          // 0..15 col group (8 cols each)
    const int row0 = blockIdx.x * 256;
    const int col0 = blockIdx.y * 128;

    // A-load: thread t loads row (row0+t), 16 consecutive k per tile
    const float* Aptr = A + (size_t)(row0 + t) * K;
    // B-load: 16 k-rows x 128 cols; thread: k=t>>4, cols (t&15)*8..+7
    const int bk = t >> 4;
    const int bc = (t & 15) * 8;
    const float* Bptr = B + (size_t)bk * N + col0 + bc;

    float scale = 1.0f;
    if (MASKED) scale = (__float_as_uint(prevNorms[row0 + t]) > thrKey[0]) ? 1.0f : 0.0f;

    float acc[16][8];
    #pragma unroll
    for (int i = 0; i < 16; ++i)
        #pragma unroll
        for (int j = 0; j < 8; ++j) acc[i][j] = 0.0f;

    for (int k0 = 0; k0 < K; k0 += 16) {
        float4 a0 = *(const float4*)(Aptr + k0);
        float4 a1 = *(const float4*)(Aptr + k0 + 4);
        float4 a2 = *(const float4*)(Aptr + k0 + 8);
        float4 a3 = *(const float4*)(Aptr + k0 + 12);
        float4 b0 = *(const float4*)(Bptr + (size_t)k0 * N);
        float4 b1 = *(const float4*)(Bptr + (size_t)k0 * N + 4);
        if (MASKED) {
            a0.x *= scale; a0.y *= scale; a0.z *= scale; a0.w *= scale;
            a1.x *= scale; a1.y *= scale; a1.z *= scale; a1.w *= scale;
            a2.x *= scale; a2.y *= scale; a2.z *= scale; a2.w *= scale;
            a3.x *= scale; a3.y *= scale; a3.z *= scale; a3.w *= scale;
        }
        As[ 0][t] = a0.x; As[ 1][t] = a0.y; As[ 2][t] = a0.z; As[ 3][t] = a0.w;
        As[ 4][t] = a1.x; As[ 5][t] = a1.y; As[ 6][t] = a1.z; As[ 7][t] = a1.w;
        As[ 8][t] = a2.x; As[ 9][t] = a2.y; As[10][t] = a2.z; As[11][t] = a2.w;
        As[12][t] = a3.x; As[13][t] = a3.y; As[14][t] = a3.z; As[15][t] = a3.w;
        *(float4*)&Bs[bk][bc]     = b0;
        *(float4*)&Bs[bk][bc + 4] = b1;
        __syncthreads();
        #pragma unroll
        for (int kk = 0; kk < 16; ++kk) {
            float a_[16], b_[8];
            *(float4*)&a_[0]  = *(const float4*)&As[kk][tr*16];
            *(float4*)&a_[4]  = *(const float4*)&As[kk][tr*16 + 4];
            *(float4*)&a_[8]  = *(const float4*)&As[kk][tr*16 + 8];
            *(float4*)&a_[12] = *(const float4*)&As[kk][tr*16 + 12];
            *(float4*)&b_[0]  = *(const float4*)&Bs[kk][tc*8];
            *(float4*)&b_[4]  = *(const float4*)&Bs[kk][tc*8 + 4];
            #pragma unroll
            for (int i = 0; i < 16; ++i)
                #pragma unroll
                for (int j = 0; j < 8; ++j)
                    acc[i][j] = fmaf(a_[i], b_[j], acc[i][j]);
        }
        __syncthreads();
    }

    float bv[8];
    #pragma unroll
    for (int j = 0; j < 8; ++j) bv[j] = bias[col0 + tc*8 + j];

    float rowsum[16];
    #pragma unroll
    for (int i = 0; i < 16; ++i) {
        float s = 0.0f;
        #pragma unroll
        for (int j = 0; j < 8; ++j) {
            float v = fmaxf(acc[i][j] + bv[j], 0.0f);   // dot, +bias, relu (matches ref)
            acc[i][j] = v;
            s = fmaf(v, v, s);
        }
        rowsum[i] = s;
    }

    #pragma unroll
    for (int i = 0; i < 16; ++i) {
        const size_t row = (size_t)(row0 + tr*16 + i);
        *(float4*)&C[row * N + col0 + tc*8]     = *(float4*)&acc[i][0];
        *(float4*)&C[row * N + col0 + tc*8 + 4] = *(float4*)&acc[i][4];
    }

    float (*red)[17] = (float(*)[17])smem;              // 17408 B overlay, safe after final barrier
    #pragma unroll
    for (int i = 0; i < 16; ++i) red[tr*16 + i][tc] = rowsum[i];
    __syncthreads();
    {
        float s = 0.0f;
        #pragma unroll
        for (int x = 0; x < 16; ++x) s += red[t][x];    // fixed order -> deterministic
        normPart[(size_t)blockIdx.y * BATCH + row0 + t] = s;
    }
}

// ============ deterministic partial-sum -> norm (sqrt in double = correctly-rounded fp32 sqrt) ============
__global__ __launch_bounds__(256)
void reduce_norms_kernel(const float* __restrict__ part, float* __restrict__ norms, const int nPart)
{
    const int i = blockIdx.x * 256 + threadIdx.x;
    float s = 0.0f;
    for (int p = 0; p < nPart; ++p) s += part[(size_t)p * BATCH + i];
    norms[i] = (float)sqrt((double)s);
}

// ============ exact 32769-th-largest: adaptive histogram + in-bin candidate rank (single WG) ============
__global__ __launch_bounds__(1024)
void select_kernel(const float* __restrict__ norms, unsigned* __restrict__ thrOut)
{
    __shared__ unsigned hist[4096];
    __shared__ unsigned ssum[1024];
    __shared__ unsigned cand[CAND_CAP];
    __shared__ unsigned wmin[16], wmax[16], gsum[16], wsum[16];
    __shared__ unsigned sMin, sBin, sRank, sCount, sThr, sApp;
    __shared__ int      sShift;

    const int t = threadIdx.x;
    unsigned key[64];
    const float4* n4p = (const float4*)norms;
    #pragma unroll
    for (int i = 0; i < 16; ++i) {
        float4 v = n4p[i * 1024 + t];
        key[i*4+0] = __float_as_uint(v.x);
        key[i*4+1] = __float_as_uint(v.y);
        key[i*4+2] = __float_as_uint(v.z);
        key[i*4+3] = __float_as_uint(v.w);          // nonneg -> monotone uint order
    }

    unsigned mn = key[0], mx = key[0];
    #pragma unroll
    for (int i = 1; i < 64; ++i) { mn = min(mn, key[i]); mx = max(mx, key[i]); }
    #pragma unroll
    for (int off = 32; off > 0; off >>= 1) {
        mn = min(mn, (unsigned)__shfl_down((int)mn, off, 64));
        mx = max(mx, (unsigned)__shfl_down((int)mx, off, 64));
    }
    if ((t & 63) == 0) { wmin[t >> 6] = mn; wmax[t >> 6] = mx; }
    hist[t] = 0; hist[t+1024] = 0; hist[t+2048] = 0; hist[t+3072] = 0;
    __syncthreads();
    if (t == 0) {
        unsigned m0 = wmin[0], m1 = wmax[0];
        for (int q = 1; q < 16; ++q) { m0 = min(m0, wmin[q]); m1 = max(m1, wmax[q]); }
        const unsigned span = m1 - m0;
        sMin = m0;
        sShift = (span > 4095u) ? (20 - __clz(span)) : 0;   // bins = span>>shift <= 4095
        sApp = 0;
    }
    __syncthreads();
    const unsigned mn_u = sMin;
    const int sh = sShift;
    #pragma unroll
    for (int i = 0; i < 64; ++i) atomicAdd(&hist[(key[i] - mn_u) >> sh], 1u);
    __syncthreads();
    ssum[t] = hist[4*t] + hist[4*t+1] + hist[4*t+2] + hist[4*t+3];
    __syncthreads();
    if (t < 16) {
        unsigned g = 0;
        for (int q = 0; q < 64; ++q) g += ssum[t*64 + q];
        gsum[t] = g;
    }
    __syncthreads();
    if (t == 0) {
        unsigned cum = 0; int g, q, b;
        for (g = 15; g >= 0; --g) { if (cum + gsum[g] >= RANK_K) break; cum += gsum[g]; }
        for (q = g*64 + 63; q >= g*64; --q) { if (cum + ssum[q] >= RANK_K) break; cum += ssum[q]; }
        for (b = q*4 + 3; b >= q*4; --b) { if (cum + hist[b] >= RANK_K) break; cum += hist[b]; }
        sBin = (unsigned)b; sRank = RANK_K - cum; sCount = hist[b];
    }
    __syncthreads();
    const unsigned b = sBin, cnt = sCount;
    const int r = (int)sRank;

    if (cnt <= CAND_CAP) {
        #pragma unroll
        for (int i = 0; i < 64; ++i)
            if (((key[i] - mn_u) >> sh) == b) { unsigned p = atomicAdd(&sApp, 1u); cand[p] = key[i]; }
        __syncthreads();
        for (int j = t; j < (int)cnt; j += 1024) {
            const unsigned kj = cand[j];
            int gq = 0, eq = 0;
            for (int i = 0; i < (int)cnt; ++i) { const unsigned ki = cand[i]; gq += ki > kj; eq += ki == kj; }
            if (gq < r && r <= gq + eq) sThr = kj;     // all writers (ties) write same value
        }
        __syncthreads();
    } else {
        // fallback (pathological clustering): binary search within bin's subrange
        unsigned lo = mn_u + (b << sh);
        unsigned hi = lo + ((sh > 0) ? ((1u << sh) - 1u) : 0u);
        while (lo < hi) {
            const unsigned mid = lo + ((hi - lo) >> 1);
            int c = 0;
            #pragma unroll
            for (int i = 0; i < 64; ++i) c += (key[i] > mid) ? 1 : 0;
            #pragma unroll
            for (int off = 32; off > 0; off >>= 1) c += __shfl_down(c, off, 64);
            if ((t & 63) == 0) wsum[t >> 6] = (unsigned)c;
            __syncthreads();
            int total = 0;
            #pragma unroll
            for (int q = 0; q < 16; ++q) total += (int)wsum[q];
            if (total < RANK_K) hi = mid; else lo = mid + 1;
            __syncthreads();
        }
        if (t == 0) sThr = lo;
        __syncthreads();
    }
    if (t == 0) thrOut[0] = sThr;
}

// ============ layer 3: h3 = relu((h2*m2) @ W3[256x10] + b3), full row norms ============
__global__ __launch_bounds__(256)
void layer3_kernel(const float* __restrict__ h2, const float* __restrict__ W3,
                   const float* __restrict__ b3,
                   const float* __restrict__ n2, const unsigned* __restrict__ thr2,
                   float* __restrict__ h3, float* __restrict__ norms3)
{
    __shared__ float wT[10][260];
    __shared__ float red[64][5];

    const int t    = threadIdx.x;
    const int r    = t & 63;
    const int g    = t >> 6;
    const int j0   = g * 3;
    const int nj   = (g == 3) ? 1 : 3;
    const int row0 = blockIdx.x * 64;
    const int row  = row0 + r;

    for (int e = t; e < 2560; e += 256) wT[e % 10][e / 10] = W3[e];
    __syncthreads();

    const float m = (__float_as_uint(n2[row]) > thr2[0]) ? 1.0f : 0.0f;
    const float* hrow = h2 + (size_t)row * 256;

    float acc[3] = {0.0f, 0.0f, 0.0f};
    for (int k = 0; k < 256; k += 4) {
        float4 v = *(const float4*)(hrow + k);
        v.x *= m; v.y *= m; v.z *= m; v.w *= m;
        float4 w0 = *(const float4*)&wT[j0][k];
        acc[0] += v.x*w0.x + v.y*w0.y + v.z*w0.z + v.w*w0.w;
        if (nj > 1) {
            float4 w1 = *(const float4*)&wT[j0+1][k];
            acc[1] += v.x*w1.x + v.y*w1.y + v.z*w1.z + v.w*w1.w;
            float4 w2 = *(const float4*)&wT[j0+2][k];
            acc[2] += v.x*w2.x + v.y*w2.y + v.z*w2.z + v.w*w2.w;
        }
    }

    float ss = 0.0f;
    for (int jj = 0; jj < nj; ++jj) {
        float v = fmaxf(acc[jj] + b3[j0 + jj], 0.0f);
        h3[(size_t)row * 10 + j0 + jj] = v;
        ss += v * v;
    }
    red[r][g] = ss;
    __syncthreads();
    if (t < 64) {
        float s = red[t][0] + red[t][1] + red[t][2] + red[t][3];
        norms3[row0 + t] = (float)sqrt((double)s);
    }
}

// ============ layer 4: h4 = (h3*m3) @ W4[10x10] + b4 (no relu), norms ============
__global__ __launch_bounds__(256)
void layer4_kernel(const float* __restrict__ h3, const float* __restrict__ W4,
                   const float* __restrict__ b4,
                   const float* __restrict__ n3, const unsigned* __restrict__ thr3,
                   float* __restrict__ h4, float* __restrict__ norms4)
{
    __shared__ float w[100];
    __shared__ float bb[10];
    const int t = threadIdx.x;
    if (t < 100) w[t] = W4[t];
    if (t < 10)  bb[t] = b4[t];
    __syncthreads();

    const int row = blockIdx.x * 256 + t;
    const float m = (__float_as_uint(n3[row]) > thr3[0]) ? 1.0f : 0.0f;
    const float* hr = h3 + (size_t)row * 10;
    float v[10];
    #pragma unroll
    for (int k = 0; k < 10; ++k) v[k] = hr[k] * m;

    float s = 0.0f;
    #pragma unroll
    for (int j = 0; j < 10; ++j) {
        float a = 0.0f;
        #pragma unroll
        for (int k = 0; k < 10; ++k) a = fmaf(v[k], w[k*10 + j], a);
        a += bb[j];
        h4[(size_t)row * 10 + j] = a;
        s = fmaf(a, a, s);
    }
    norms4[row] = (float)sqrt((double)s);
}

// ============ final: out = softmax(h4 * m4) ============
__global__ __launch_bounds__(256)
void softmax_kernel(const float* __restrict__ h4,
                    const float* __restrict__ n4, const unsigned* __restrict__ thr4,
                    float* __restrict__ out)
{
    const int t   = threadIdx.x;
    const int row = blockIdx.x * 256 + t;
    const float m = (__float_as_uint(n4[row]) > thr4[0]) ? 1.0f : 0.0f;
    const float* hr = h4 + (size_t)row * 10;
    float v[10];
    #pragma unroll
    for (int k = 0; k < 10; ++k) v[k] = hr[k] * m;
    float mx = v[0];
    #pragma unroll
    for (int k = 1; k < 10; ++k) mx = fmaxf(mx, v[k]);
    float e[10];
    float s = 0.0f;
    #pragma unroll
    for (int k = 0; k < 10; ++k) { e[k] = expf(v[k] - mx); s += e[k]; }
    const float inv = 1.0f / s;
    #pragma unroll
    for (int k = 0; k < 10; ++k) out[(size_t)row * 10 + k] = e[k] * inv;
}

// ============ materialize all four masks into d_out ============
__global__ __launch_bounds__(256)
void masks_kernel(const float* __restrict__ n1, const float* __restrict__ n2,
                  const float* __restrict__ n3, const float* __restrict__ n4,
                  const unsigned* __restrict__ thr,
                  float* __restrict__ m1, float* __restrict__ m2,
                  float* __restrict__ m3, float* __restrict__ m4)
{
    const int i = blockIdx.x * 256 + threadIdx.x;
    m1[i] = (__float_as_uint(n1[i]) > thr[0]) ? 1.0f : 0.0f;
    m2[i] = (__float_as_uint(n2[i]) > thr[1]) ? 1.0f : 0.0f;
    m3[i] = (__float_as_uint(n3[i]) > thr[2]) ? 1.0f : 0.0f;
    m4[i] = (__float_as_uint(n4[i]) > thr[3]) ? 1.0f : 0.0f;
}

extern "C" void kernel_launch(void* const* d_in, const int* in_sizes, int n_in,
                              void* d_out, int out_size, void* d_ws, size_t ws_size,
                              hipStream_t stream)
{
    const float* x  = (const float*)d_in[0];
    const float* W1 = (const float*)d_in[1];
    const float* b1 = (const float*)d_in[2];
    const float* W2 = (const float*)d_in[3];
    const float* b2 = (const float*)d_in[4];
    const float* W3 = (const float*)d_in[5];
    const float* b3 = (const float*)d_in[6];
    const float* W4 = (const float*)d_in[7];
    const float* b4 = (const float*)d_in[8];

    float* out = (float*)d_out;                 // [65536,10]
    float* m1  = out + (size_t)BATCH * 10;      // [65536] each
    float* m2  = m1 + BATCH;
    float* m3  = m2 + BATCH;
    float* m4  = m3 + BATCH;

    float* ws    = (float*)d_ws;
    float* h1    = ws;                                  // 65536*512
    float* h2    = h1 + (size_t)BATCH * 512;            // 65536*256
    float* h3    = h2 + (size_t)BATCH * 256;            // 65536*10
    float* h4    = h3 + (size_t)BATCH * 10;             // 65536*10
    float* n1    = h4 + (size_t)BATCH * 10;             // 65536 x4
    float* n2    = n1 + BATCH;
    float* n3    = n2 + BATCH;
    float* n4    = n3 + BATCH;
    float* part  = n4 + BATCH;                          // 4*65536
    unsigned* thr = (unsigned*)(part + (size_t)4 * BATCH);  // 4 threshold keys

    // layer 1: x[65536,784] @ W1[784,512]
    gemm_relu_norm<false><<<dim3(256, 4), 256, 0, stream>>>(x, W1, b1, nullptr, nullptr, h1, part, 512, 784);
    reduce_norms_kernel<<<256, 256, 0, stream>>>(part, n1, 4);
    select_kernel<<<1, 1024, 0, stream>>>(n1, thr + 0);

    // layer 2: (h1*m1)[65536,512] @ W2[512,256]  (mask inline from n1/thr1)
    gemm_relu_norm<true><<<dim3(256, 2), 256, 0, stream>>>(h1, W2, b2, n1, thr + 0, h2, part, 256, 512);
    reduce_norms_kernel<<<256, 256, 0, stream>>>(part, n2, 2);
    select_kernel<<<1, 1024, 0, stream>>>(n2, thr + 1);

    // layer 3: (h2*m2)[65536,256] @ W3[256,10]
    layer3_kernel<<<1024, 256, 0, stream>>>(h2, W3, b3, n2, thr + 1, h3, n3);
    select_kernel<<<1, 1024, 0, stream>>>(n3, thr + 2);

    // layer 4: (h3*m3)[65536,10] @ W4[10,10] (no relu)
    layer4_kernel<<<256, 256, 0, stream>>>(h3, W4, b4, n3, thr + 2, h4, n4);
    select_kernel<<<1, 1024, 0, stream>>>(n4, thr + 3);

    // softmax(h4*m4)
    softmax_kernel<<<256, 256, 0, stream>>>(h4, n4, thr + 3, out);

    // masks m1..m4 -> d_out
    masks_kernel<<<256, 256, 0, stream>>>(n1, n2, n3, n4, thr, m1, m2, m3, m4);
}